// Round 7
// baseline (265.144 us; speedup 1.0000x reference)
//
#include <hip/hip_runtime.h>

// Problem constants (from reference setup_inputs)
#define B_ 64
#define C_ 256
#define T_ 2048
#define EPS_ 1e-4f
#define NPC ((float)(B_ * T_))   // elements per channel = 131072

#define T4 (T_ / 4)              // 512 vec4 per row
#define CG_ 8                    // channels per stats slab (64 KiB contiguous)

// Norm tiling: block = 4 waves; wave w owns channel c0+w, lanes own 64
// consecutive t4 -> every global access is 1 KB contiguous per wave.
#define BCHUNK 32

typedef float f4 __attribute__((ext_vector_type(4)));

// ---------------------------------------------------------------------------
// Kernel 1: slab stats. Grid = B_*(C_/CG_) = 2048 blocks of 256.
// Block (b, cg) reads ONE contiguous 64 KiB slab: channels cg*8..cg*8+7 of
// batch b. Channel-uniform accumulation acc[i>>1]; LDS transpose reduce.
//   partials layout (TRANSPOSED for coalesced finalize): [sum: [C][B]][ssq: [C][B]]
// ---------------------------------------------------------------------------
__global__ __launch_bounds__(256) void bntt_stats(const float* __restrict__ x,
                                                  float* __restrict__ partials) {
    const int bid = blockIdx.x;
    const int b   = bid >> 5;            // 64 batches
    const int cg  = bid & 31;            // 32 channel-groups of 8
    const int tid = threadIdx.x;
    const f4* p = (const f4*)(x + ((size_t)b * C_ + (size_t)cg * CG_) * T_);

    float sum[CG_], ssq[CG_];
    #pragma unroll
    for (int k = 0; k < CG_; ++k) { sum[k] = 0.0f; ssq[k] = 0.0f; }

    #pragma unroll
    for (int i = 0; i < 16; ++i) {       // slab = 4096 f4; channel = i>>1
        f4 v = p[tid + i * 256];
        const int k = i >> 1;
        sum[k] += v.x + v.y + v.z + v.w;
        ssq[k] += v.x * v.x + v.y * v.y + v.z * v.z + v.w * v.w;
    }

    __shared__ float ls[CG_][256];
    __shared__ float lq[CG_][256];
    #pragma unroll
    for (int k = 0; k < CG_; ++k) { ls[k][tid] = sum[k]; lq[k][tid] = ssq[k]; }
    __syncthreads();

    const int k = tid >> 5;              // channel 0..7 within slab
    const int j = tid & 31;              // lane within 32-group
    float S = 0.0f, SS = 0.0f;
    #pragma unroll
    for (int m = 0; m < 8; ++m) {
        S  += ls[k][j + m * 32];
        SS += lq[k][j + m * 32];
    }
    #pragma unroll
    for (int off = 16; off > 0; off >>= 1) {
        S  += __shfl_down(S, off);
        SS += __shfl_down(SS, off);
    }
    if (j == 0) {
        const size_t c = (size_t)cg * CG_ + k;
        partials[c * B_ + b]                       = S;    // [c][b]
        partials[(size_t)C_ * B_ + c * B_ + b]     = SS;
    }
}

// ---------------------------------------------------------------------------
// Kernel 2: finalize + normalize, wave-contiguous, PLAIN (cached) stores.
// Grid = 1024 blocks x 256 threads (4 waves):
//   tile = bid & 511: cq = tile>>3 -> c0 = cq*4;  tq = tile&7 -> t4base = tq*64
//   b0   = (bid>>9) * BCHUNK
// A/B vs R6: the ONLY change is nontemporal -> regular stores. The fill
// kernel demonstrates 6.5+ TB/s with cached stores; NT was the one invariant
// across every ~90 us kernel-pair variant.
// ---------------------------------------------------------------------------
__global__ __launch_bounds__(256) void bntt_norm(const float* __restrict__ x,
                                                 const float* __restrict__ gamma,
                                                 const float* __restrict__ beta,
                                                 const float* __restrict__ partials,
                                                 float* __restrict__ out) {
    __shared__ float sg[4][256];         // [c_local][t_local]
    __shared__ float sb[4][256];
    __shared__ float smean[4], sistd[4];

    const int tid    = threadIdx.x;
    const int tile   = blockIdx.x & 511;
    const int c0     = (tile >> 3) * 4;          // 64 channel-quads
    const int t4base = (tile & 7) * 64;          // 8 t4-tiles of 64
    const int b0     = (blockIdx.x >> 9) * BCHUNK;

    // stage gamma/beta: thread tid handles t-row tbase+tid, 4 channels via f4
    {
        const int tbase = t4base * 4;
        const size_t gi = (size_t)(tbase + tid) * C_ + c0;   // 16B-aligned
        f4 g = *(const f4*)&gamma[gi];
        f4 bb = *(const f4*)&beta[gi];
        #pragma unroll
        for (int c = 0; c < 4; ++c) {
            sg[c][tid] = ((const float*)&g)[c];
            sb[c][tid] = ((const float*)&bb)[c];
        }
    }

    // finalize stats: thread (c, b); coalesced [c][b] loads; 64-lane reduce
    {
        const int c = tid >> 6;                  // 0..3 (== wave id)
        const int b = tid & 63;
        const size_t cc = (size_t)(c0 + c);
        float S  = partials[cc * B_ + b];
        float SS = partials[(size_t)C_ * B_ + cc * B_ + b];
        #pragma unroll
        for (int off = 32; off > 0; off >>= 1) {
            S  += __shfl_down(S, off);
            SS += __shfl_down(SS, off);
        }
        if (b == 0) {
            const float mean = S / NPC;
            smean[c] = mean;
            sistd[c] = rsqrtf(SS / NPC - mean * mean + EPS_);
        }
    }
    __syncthreads();

    // per-thread affine: wave w -> channel c0+w; lane -> t4 = t4base+lane
    const int w    = tid >> 6;
    const int lane = tid & 63;
    const float mean = smean[w];
    const float istd = sistd[w];
    f4 sc, sh;
    {
        const f4 g4 = *(const f4*)&sg[w][lane * 4];   // 16B-aligned LDS read
        const f4 b4 = *(const f4*)&sb[w][lane * 4];
        #pragma unroll
        for (int j = 0; j < 4; ++j) {
            const float s1 = ((const float*)&g4)[j] * istd;
            ((float*)&sc)[j] = s1;
            ((float*)&sh)[j] = fmaf(-mean, s1, ((const float*)&b4)[j]);
        }
    }

    // stream 32 batch rows: wave-contiguous 1 KB load + 1 KB cached store
    size_t idx = ((size_t)b0 * C_ + (c0 + w)) * T4 + (t4base + lane);
    const size_t step = (size_t)C_ * T4;         // one batch row
    #pragma unroll 8
    for (int b = 0; b < BCHUNK; ++b) {
        f4 xv = ((const f4*)x)[idx];
        f4 o;
        o.x = fmaf(xv.x, sc.x, sh.x);
        o.y = fmaf(xv.y, sc.y, sh.y);
        o.z = fmaf(xv.z, sc.z, sh.z);
        o.w = fmaf(xv.w, sc.w, sh.w);
        ((f4*)out)[idx] = o;                     // plain store (was NT)
        idx += step;
    }
}

// ---------------------------------------------------------------------------
// Fallback (ws < 128 KB): 8-split stats (16 KB partials) + direct norm.
// ---------------------------------------------------------------------------
#define SPLITS 8
#define BPB (B_ / SPLITS)
__global__ __launch_bounds__(256) void bntt_stats_fb(const float* __restrict__ x,
                                                     float* __restrict__ partials) {
    const int c   = blockIdx.x & (C_ - 1);
    const int s   = blockIdx.x >> 8;
    const int tid = threadIdx.x;
    float sum = 0.0f, sumsq = 0.0f;
    const int b0 = s * BPB;
    #pragma unroll
    for (int b = 0; b < BPB; ++b) {
        const f4* p = (const f4*)(x + (size_t)(b0 + b) * (C_ * T_) + (size_t)c * T_);
        #pragma unroll
        for (int i = 0; i < T4 / 256; ++i) {
            f4 v = p[tid + i * 256];
            sum   += v.x + v.y + v.z + v.w;
            sumsq += v.x * v.x + v.y * v.y + v.z * v.z + v.w * v.w;
        }
    }
    #pragma unroll
    for (int off = 32; off > 0; off >>= 1) {
        sum   += __shfl_down(sum, off);
        sumsq += __shfl_down(sumsq, off);
    }
    __shared__ float ls2[4], lss2[4];
    const int wave = tid >> 6, lane = tid & 63;
    if (lane == 0) { ls2[wave] = sum; lss2[wave] = sumsq; }
    __syncthreads();
    if (tid == 0) {
        partials[s * C_ + c]               = ls2[0] + ls2[1] + ls2[2] + ls2[3];
        partials[SPLITS * C_ + s * C_ + c] = lss2[0] + lss2[1] + lss2[2] + lss2[3];
    }
}

__global__ __launch_bounds__(256) void bntt_norm_fb(const float* __restrict__ x,
                                                    const float* __restrict__ gamma,
                                                    const float* __restrict__ beta,
                                                    const float* __restrict__ partials,
                                                    float* __restrict__ out) {
    const int p   = (blockIdx.x & 511) * 256 + threadIdx.x;
    const int c   = p >> 9;
    const int t4  = p & (T4 - 1);
    const int t   = t4 * 4;
    const int b0  = (blockIdx.x >> 9) * BCHUNK;

    float S = 0.0f, SS = 0.0f;
    #pragma unroll
    for (int s = 0; s < SPLITS; ++s) {
        S  += partials[s * C_ + c];
        SS += partials[SPLITS * C_ + s * C_ + c];
    }
    const float mean = S / NPC;
    const float istd = rsqrtf(SS / NPC - mean * mean + EPS_);

    f4 sc, sh;
    #pragma unroll
    for (int j = 0; j < 4; ++j) {
        float g  = gamma[(size_t)(t + j) * C_ + c];
        float bb = beta [(size_t)(t + j) * C_ + c];
        float s1 = g * istd;
        ((float*)&sc)[j] = s1;
        ((float*)&sh)[j] = fmaf(-mean, s1, bb);
    }
    size_t idx = (size_t)(b0 * C_ + c) * T4 + t4;
    const size_t step = (size_t)C_ * T4;
    #pragma unroll 8
    for (int b = 0; b < BCHUNK; ++b) {
        f4 xv = ((const f4*)x)[idx];
        f4 o;
        o.x = fmaf(xv.x, sc.x, sh.x);
        o.y = fmaf(xv.y, sc.y, sh.y);
        o.z = fmaf(xv.z, sc.z, sh.z);
        o.w = fmaf(xv.w, sc.w, sh.w);
        ((f4*)out)[idx] = o;                     // plain store (was NT)
        idx += step;
    }
}

extern "C" void kernel_launch(void* const* d_in, const int* in_sizes, int n_in,
                              void* d_out, int out_size, void* d_ws, size_t ws_size,
                              hipStream_t stream) {
    const float* x     = (const float*)d_in[0];
    const float* gamma = (const float*)d_in[1];
    const float* beta  = (const float*)d_in[2];
    float* out = (float*)d_out;
    float* partials = (float*)d_ws;

    const int ngrid = 1024;   // 512 (c,t4) tiles x 2 b-halves

    if (ws_size >= (size_t)2 * B_ * C_ * sizeof(float)) {            // 128 KB
        bntt_stats<<<B_ * (C_ / CG_), 256, 0, stream>>>(x, partials);
        bntt_norm<<<ngrid, 256, 0, stream>>>(x, gamma, beta, partials, out);
    } else {
        bntt_stats_fb<<<C_ * SPLITS, 256, 0, stream>>>(x, partials);
        bntt_norm_fb<<<ngrid, 256, 0, stream>>>(x, gamma, beta, partials, out);
    }
}